// Round 10
// baseline (202.340 us; speedup 1.0000x reference)
//
#include <hip/hip_runtime.h>

#define TSEQ 2048
#define CDIM 1024
#define NH 16
#define DH 64
#define NB 4

typedef __bf16 bf16x8 __attribute__((ext_vector_type(8)));
typedef float f32x4 __attribute__((ext_vector_type(4)));

// 1/sqrt(C) * log2(e): folded into Q so softmax runs in exp2 domain
#define QSCALE 0.04508422f

static __device__ __forceinline__ ushort f2bf(float f) {
  unsigned u = __float_as_uint(f);
  unsigned r = u + 0x7fffu + ((u >> 16) & 1u);
  return (ushort)(r >> 16);
}

static __device__ __forceinline__ uint cvtpk(float lo, float hi) {
  uint r;
  asm("v_cvt_pk_bf16_f32 %0, %1, %2" : "=v"(r) : "v"(lo), "v"(hi));
  return r;
}

// global(16B, per-lane addr) -> LDS (wave-uniform base, HW adds lane*16)
static __device__ __forceinline__ void gload_lds16(const void* g, void* ldsbase) {
  __builtin_amdgcn_global_load_lds((const __attribute__((address_space(1))) void*)g,
                                   (__attribute__((address_space(3))) void*)ldsbase,
                                   16, 0, 0);
}

__global__ void cvt_x_kernel(const float4* __restrict__ src, ushort4* __restrict__ dst, int n4) {
  int i = blockIdx.x * blockDim.x + threadIdx.x;
  if (i >= n4) return;
  float4 f = src[i];
  ushort4 o;
  o.x = f2bf(f.x); o.y = f2bf(f.y); o.z = f2bf(f.z); o.w = f2bf(f.w);
  dst[i] = o;
}

// All weight transposes in ONE launch. z<3: W{q,k,v}[16][1024][64] -> wall slice
// [z][head][64][1024]; z==3: Wp[1024][1024] -> wpT[1024][1024].
__global__ void transpose_cvt_all(const float* __restrict__ Wq, const float* __restrict__ Wk,
                                  const float* __restrict__ Wv, const float* __restrict__ Wp,
                                  ushort* __restrict__ wall, ushort* __restrict__ wpT) {
  __shared__ float tile[32][33];
  const int z = blockIdx.z;
  const float* s; ushort* d; int Cc, c0, r0;
  if (z < 3) {
    const int head = blockIdx.x >> 1;
    s = (z == 0 ? Wq : z == 1 ? Wk : Wv) + (size_t)head * CDIM * DH;
    d = wall + ((size_t)z << 20) + (size_t)head * CDIM * DH;
    Cc = DH; c0 = (blockIdx.x & 1) * 32; r0 = blockIdx.y * 32;
  } else {
    s = Wp; d = wpT; Cc = CDIM; c0 = blockIdx.x * 32; r0 = blockIdx.y * 32;
  }
  const int tx = threadIdx.x, ty = threadIdx.y;
  for (int i = ty; i < 32; i += 8)
    tile[i][tx] = s[(size_t)(r0 + i) * Cc + c0 + tx];
  __syncthreads();
  for (int i = ty; i < 32; i += 8)
    d[(size_t)(c0 + i) * CDIM + r0 + tx] = f2bf(tile[tx][i]);
}

// 128x128-tile GEMM over A[8192][1024] @ B^T[N][1024], K=1024, BK=32,
// DOUBLE-BUFFERED at 32KB total LDS: one barrier per step, stage(k+1) issued
// before compute(k). launch_bounds(256,4) caps VGPR at 128 -> 4 waves/SIMD.
// Rows are 64B; swizzle chunk ^= (row>>1)&3 is conflict-free on ds_read_b128.
// MODE 0: qkv (B^T = [3072][1024]; route by n). MODE 1: proj (f32 + bias).
// XCD chunk is nt-fastest: each XCD reads only 8 A-panels (2 MB, L2-resident).
template <int MODE>
__global__ __launch_bounds__(256, 4) void gemm_kernel(
    const ushort* __restrict__ A, const ushort* __restrict__ Bt,
    const float* __restrict__ bp, float* __restrict__ fout,
    ushort* __restrict__ qb, ushort* __restrict__ kb, ushort* __restrict__ vTb) {
  __shared__ ushort lds[16384]; // 2 buf x (A 8KB + B 8KB) = 32KB
  const int tid = threadIdx.x, w = tid >> 6, l = tid & 63;
  const int nwg = gridDim.x;
  const int bid = blockIdx.x;
  const int wgid = (bid & 7) * (nwg >> 3) + (bid >> 3); // XCD swizzle (nwg % 8 == 0)
  const int NT = (MODE == 0) ? 24 : 8;
  const int nt = wgid % NT, mt = wgid / NT; // nt-fastest within an XCD chunk
  const int wr = w >> 1, wc = w & 1;
  const int srw = l >> 2;                      // row within a 16-row issue group
  const int sck = l & 3;                       // stored 16B chunk
  const int scol = (sck ^ ((srw >> 1) & 3)) * 8; // logical col (elems) this lane loads
  const int g = l >> 4;
  char* ldsb = (char*)lds;

  f32x4 acc[4][4] = {};

  const ushort* Arow = A + ((size_t)mt * 128) * CDIM;
  const ushort* Brow = Bt + ((size_t)nt * 128) * CDIM;

  // prologue: stage k0=0 into buf 0 (A: ch 0-7, B: ch 8-15; 16 rows per chunk)
#pragma unroll
  for (int i = 0; i < 4; ++i) {
    int ch = w * 4 + i;
    const ushort* src = (ch < 8) ? Arow + (size_t)(ch * 16 + srw) * CDIM + scol
                                 : Brow + (size_t)((ch - 8) * 16 + srw) * CDIM + scol;
    gload_lds16(src, ldsb + ch * 1024);
  }

  for (int k0 = 0; k0 < CDIM; k0 += 32) {
    const int bsel = (k0 >> 5) & 1;
    char* base = ldsb + bsel * 16384;
    __syncthreads(); // buf[bsel] ready; buf[bsel^1] free
    if (k0 + 32 < CDIM) { // issue next-tile loads; latency hides under compute below
      char* nb = ldsb + (bsel ^ 1) * 16384;
#pragma unroll
      for (int i = 0; i < 4; ++i) {
        int ch = w * 4 + i;
        const ushort* src = (ch < 8)
            ? Arow + (size_t)(ch * 16 + srw) * CDIM + k0 + 32 + scol
            : Brow + (size_t)((ch - 8) * 16 + srw) * CDIM + k0 + 32 + scol;
        gload_lds16(src, nb + ch * 1024);
      }
    }
    bf16x8 af[4];
#pragma unroll
    for (int fm = 0; fm < 4; ++fm) {
      int row = wr * 64 + fm * 16 + (l & 15);
      af[fm] = *(const bf16x8*)(base + row * 64 + ((g ^ ((row >> 1) & 3)) << 4));
    }
#pragma unroll
    for (int fn = 0; fn < 4; ++fn) {
      int n = wc * 64 + fn * 16 + (l & 15);
      bf16x8 bfr = *(const bf16x8*)(base + 8192 + n * 64 + ((g ^ ((n >> 1) & 3)) << 4));
#pragma unroll
      for (int fm = 0; fm < 4; ++fm)
        acc[fm][fn] = __builtin_amdgcn_mfma_f32_16x16x32_bf16(af[fm], bfr, acc[fm][fn], 0, 0, 0);
    }
  }

#pragma unroll
  for (int fm = 0; fm < 4; ++fm) {
#pragma unroll
    for (int fn = 0; fn < 4; ++fn) {
      const int gr0 = mt * 128 + wr * 64 + fm * 16 + (l >> 4) * 4;
      const int gc = nt * 128 + wc * 64 + fn * 16 + (l & 15);
      if (MODE == 1) {
        float bias = bp[gc];
#pragma unroll
        for (int r = 0; r < 4; ++r)
          fout[(size_t)(gr0 + r) * CDIM + gc] = acc[fm][fn][r] + bias;
      } else {
        const int sel = gc >> 10, h = (gc >> 6) & 15, d = gc & 63;
        const int bh = (gr0 >> 11) * NH + h, tl = gr0 & 2047;
        if (sel == 2) {
          ushort4 pk;
          pk.x = f2bf(acc[fm][fn][0]); pk.y = f2bf(acc[fm][fn][1]);
          pk.z = f2bf(acc[fm][fn][2]); pk.w = f2bf(acc[fm][fn][3]);
          *(ushort4*)(vTb + ((size_t)bh * DH + d) * TSEQ + tl) = pk;
        } else if (sel == 0) {
#pragma unroll
          for (int r = 0; r < 4; ++r)
            qb[((size_t)bh * TSEQ + tl + r) * DH + d] = f2bf(acc[fm][fn][r] * QSCALE);
        } else {
#pragma unroll
          for (int r = 0; r < 4; ++r)
            kb[((size_t)bh * TSEQ + tl + r) * DH + d] = f2bf(acc[fm][fn][r]);
        }
      }
    }
  }
}

// Flash attention: 1024 blocks x 256 threads (4 waves), one 128-q tile per block,
// qt-DESCENDING dispatch + XCD-aware bh grouping. Wave owns 32 q-rows (2 x 16-q
// subtiles sharing every K/V fragment read). KVBLK=64, double-buffered staging.
// launch_bounds(256,4) caps VGPR at 128 -> 4 waves/SIMD (16 waves/CU).
// Swapped QK^T: lane owns a q-row's k-slice. Softmax common path has NO cross-lane
// ops; lsum per-lane, reduced once at epilogue.
__global__ __launch_bounds__(256, 4) void attn_kernel(
    const ushort* __restrict__ qb, const ushort* __restrict__ kb,
    const ushort* __restrict__ vTb, ushort* __restrict__ aob) {
  __shared__ ushort lds[16384]; // K dbuf 2x8KB @0, V dbuf 2x8KB @byte 16384
  char* ldsb = (char*)lds;
  const int tid = threadIdx.x, w = tid >> 6, l = tid & 63;
  const int id = blockIdx.x;
  const int bh = (id & 7) * 8 + ((id >> 3) & 7); // XCD-aware bh grouping
  const int qt = 15 - (id >> 6);                 // big q-tiles dispatch first
  const int q0 = qt * 128;
  const int nt = 2 * (qt + 1);                   // # of 64-wide KV tiles
  const int b = bh >> 4, h = bh & 15;
  const int g = l >> 4, q = l & 15;
  const int srow = l >> 3;
  const int scol = (((l & 7) ^ srow) << 3);
  // bpermute byte-addrs: src lane = 32*(g&1) + 16*(j>=2) + q
  const int adrA = ((l & 16) << 1 | q) << 2;
  const int adrB = adrA + 64;
  const bool hi32 = (l & 32) != 0;

  bf16x8 qf[2][2]; // [qsub][ks]
#pragma unroll
  for (int qs = 0; qs < 2; ++qs) {
    const ushort* qrow = qb + ((size_t)bh * TSEQ + q0 + w * 32 + qs * 16 + q) * DH;
    qf[qs][0] = *(const bf16x8*)(qrow + 8 * g);
    qf[qs][1] = *(const bf16x8*)(qrow + 32 + 8 * g);
  }

  float m[2] = {0.f, 0.f}, lsum[2] = {0.f, 0.f}; // m=0 valid: branch fires if exceeded
  f32x4 o[4][2] = {};

  // prologue: tile 0 -> buf 0 (16 chunks over 4 waves)
#pragma unroll
  for (int i = 0; i < 4; ++i) {
    int ch = w * 4 + i;
    if (ch < 8)
      gload_lds16(kb + ((size_t)bh * TSEQ + ch * 8 + srow) * DH + scol, ldsb + ch * 1024);
    else {
      int d = (ch - 8) * 8 + srow;
      gload_lds16(vTb + ((size_t)bh * DH + d) * TSEQ + scol, ldsb + 16384 + (ch - 8) * 1024);
    }
  }

#pragma unroll 1
  for (int j = 0; j < nt; ++j) {
    __syncthreads(); // tile j resident; buf[(j+1)&1] free
    const int cbuf = j & 1;
    if (j + 1 < nt) { // prefetch j+1; latency hides under compute of j
      const int kvn = (j + 1) * 64, nb = (j + 1) & 1;
#pragma unroll
      for (int i = 0; i < 4; ++i) {
        int ch = w * 4 + i;
        if (ch < 8)
          gload_lds16(kb + ((size_t)bh * TSEQ + kvn + ch * 8 + srow) * DH + scol,
                      ldsb + nb * 8192 + ch * 1024);
        else {
          int d = (ch - 8) * 8 + srow;
          gload_lds16(vTb + ((size_t)bh * DH + d) * TSEQ + kvn + scol,
                      ldsb + 16384 + nb * 8192 + (ch - 8) * 1024);
        }
      }
    }
    char* Kb = ldsb + cbuf * 8192;
    char* Vb = ldsb + 16384 + cbuf * 8192;

    // S^T = K @ Q^T; s[fn][qs][r] = S[q-row q0+w*32+qs*16+q][k = j*64 + fn*16+4g+r]
    f32x4 s[4][2] = {};
    __builtin_amdgcn_s_setprio(1);
#pragma unroll
    for (int ks = 0; ks < 2; ++ks)
#pragma unroll
      for (int fn = 0; fn < 4; ++fn) {
        int n = fn * 16 + q;
        int cbb = (ks * 64 + 16 * g) ^ ((n & 7) << 4);
        bf16x8 kf = *(const bf16x8*)(Kb + n * 128 + cbb); // read once, feed both qsubs
        s[fn][0] = __builtin_amdgcn_mfma_f32_16x16x32_bf16(kf, qf[0][ks], s[fn][0], 0, 0, 0);
        s[fn][1] = __builtin_amdgcn_mfma_f32_16x16x32_bf16(kf, qf[1][ks], s[fn][1], 0, 0, 0);
      }
    __builtin_amdgcn_s_setprio(0);

    if (j >= nt - 2) { // only the diagonal band needs the causal mask
#pragma unroll
      for (int qs = 0; qs < 2; ++qs) {
        int rowloc = q0 + w * 32 + qs * 16 + q - j * 64; // may be negative (safe)
#pragma unroll
        for (int fn = 0; fn < 4; ++fn)
#pragma unroll
          for (int r = 0; r < 4; ++r)
            if (fn * 16 + 4 * g + r > rowloc) s[fn][qs][r] = -1e30f;
      }
    }

    // per-lane overflow check only (no cross-lane ops in the common path)
    float vmx[2];
#pragma unroll
    for (int qs = 0; qs < 2; ++qs) {
      float v = fmaxf(fmaxf(fmaxf(s[0][qs][0], s[0][qs][1]), fmaxf(s[0][qs][2], s[0][qs][3])),
                      fmaxf(fmaxf(s[1][qs][0], s[1][qs][1]), fmaxf(s[1][qs][2], s[1][qs][3])));
      v = fmaxf(v, fmaxf(fmaxf(fmaxf(s[2][qs][0], s[2][qs][1]), fmaxf(s[2][qs][2], s[2][qs][3])),
                         fmaxf(fmaxf(s[3][qs][0], s[3][qs][1]), fmaxf(s[3][qs][2], s[3][qs][3]))));
      vmx[qs] = v;
    }
    if (__any(fmaxf(vmx[0] - m[0], vmx[1] - m[1]) > 8.f)) { // rare: full reduce + rescale
      float fc[2];
#pragma unroll
      for (int qs = 0; qs < 2; ++qs) {
        float v = vmx[qs];
        v = fmaxf(v, __shfl_xor(v, 16));
        v = fmaxf(v, __shfl_xor(v, 32));
        float mn = fmaxf(m[qs], v);
        fc[qs] = __builtin_amdgcn_exp2f(m[qs] - mn);
        m[qs] = mn; lsum[qs] *= fc[qs];
      }
#pragma unroll
      for (int r = 0; r < 4; ++r) {
        float f0 = __shfl(fc[0], (l & 0x30) | (4 * g + r), 64);
        float f1 = __shfl(fc[1], (l & 0x30) | (4 * g + r), 64);
#pragma unroll
        for (int fn = 0; fn < 4; ++fn) { o[fn][0][r] *= f0; o[fn][1][r] *= f1; }
      }
    }

    uint D[2][4][2];
#pragma unroll
    for (int qs = 0; qs < 2; ++qs) {
      float rs = 0.f;
#pragma unroll
      for (int fn = 0; fn < 4; ++fn) {
        float p0 = __builtin_amdgcn_exp2f(s[fn][qs][0] - m[qs]);
        float p1 = __builtin_amdgcn_exp2f(s[fn][qs][1] - m[qs]);
        float p2 = __builtin_amdgcn_exp2f(s[fn][qs][2] - m[qs]);
        float p3 = __builtin_amdgcn_exp2f(s[fn][qs][3] - m[qs]);
        rs += (p0 + p1) + (p2 + p3);
        D[qs][fn][0] = cvtpk(p0, p1);
        D[qs][fn][1] = cvtpk(p2, p3);
      }
      lsum[qs] += rs; // per-lane partial; cross-lane reduce deferred to epilogue
    }

    // O += P @ V over 2 k-slices of 32; V fragment read once, feeds both qsubs
#pragma unroll
    for (int ksg = 0; ksg < 2; ++ksg) {
      union { uint u[4]; bf16x8 v; } P[2];
#pragma unroll
      for (int qs = 0; qs < 2; ++qs) {
        uint t0a = __builtin_amdgcn_ds_bpermute(adrA, (int)D[qs][2 * ksg][0]);
        uint t0b = __builtin_amdgcn_ds_bpermute(adrA, (int)D[qs][2 * ksg + 1][0]);
        uint t1a = __builtin_amdgcn_ds_bpermute(adrA, (int)D[qs][2 * ksg][1]);
        uint t1b = __builtin_amdgcn_ds_bpermute(adrA, (int)D[qs][2 * ksg + 1][1]);
        uint t2a = __builtin_amdgcn_ds_bpermute(adrB, (int)D[qs][2 * ksg][0]);
        uint t2b = __builtin_amdgcn_ds_bpermute(adrB, (int)D[qs][2 * ksg + 1][0]);
        uint t3a = __builtin_amdgcn_ds_bpermute(adrB, (int)D[qs][2 * ksg][1]);
        uint t3b = __builtin_amdgcn_ds_bpermute(adrB, (int)D[qs][2 * ksg + 1][1]);
        P[qs].u[0] = hi32 ? t0b : t0a;
        P[qs].u[1] = hi32 ? t1b : t1a;
        P[qs].u[2] = hi32 ? t2b : t2a;
        P[qs].u[3] = hi32 ? t3b : t3a;
      }
      __builtin_amdgcn_s_setprio(1);
#pragma unroll
      for (int fn = 0; fn < 4; ++fn) {
        int n = fn * 16 + q;
        int cbb = (ksg * 64 + 16 * g) ^ ((n & 7) << 4);
        bf16x8 vf = *(const bf16x8*)(Vb + n * 128 + cbb);
        o[fn][0] = __builtin_amdgcn_mfma_f32_16x16x32_bf16(P[0].v, vf, o[fn][0], 0, 0, 0);
        o[fn][1] = __builtin_amdgcn_mfma_f32_16x16x32_bf16(P[1].v, vf, o[fn][1], 0, 0, 0);
      }
      __builtin_amdgcn_s_setprio(0);
    }
  }

#pragma unroll
  for (int qs = 0; qs < 2; ++qs) {
    float tot = lsum[qs];                 // combine the 4 g-replica partial sums once
    tot += __shfl_xor(tot, 16);
    tot += __shfl_xor(tot, 32);
    float inv = 1.f / tot;                // per q-column l&15
#pragma unroll
    for (int r = 0; r < 4; ++r) {
      float invq = __shfl(inv, (l & 0x30) | (4 * g + r), 64);
      int t = q0 + w * 32 + qs * 16 + 4 * g + r;
#pragma unroll
      for (int fn = 0; fn < 4; ++fn) {
        int d = fn * 16 + q;
        aob[((size_t)b * TSEQ + t) * (NH * DH) + h * DH + d] = f2bf(o[fn][qs][r] * invq);
      }
    }
  }
}

extern "C" void kernel_launch(void* const* d_in, const int* in_sizes, int n_in,
                              void* d_out, int out_size, void* d_ws, size_t ws_size,
                              hipStream_t stream) {
  (void)in_sizes; (void)n_in; (void)out_size; (void)ws_size;
  const float* x  = (const float*)d_in[0];
  const float* Wq = (const float*)d_in[1];
  const float* Wk = (const float*)d_in[2];
  const float* Wv = (const float*)d_in[3];
  const float* Wp = (const float*)d_in[4];
  const float* bp = (const float*)d_in[5];
  float* out = (float*)d_out;
  char* ws = (char*)d_ws;

  ushort* xb  = (ushort*)(ws);                      // [8192][1024] bf16
  ushort* wall = (ushort*)(ws + (16ull << 20));     // [3072][1024] = Wq^T|Wk^T|Wv^T
  ushort* wpT = (ushort*)(ws + (22ull << 20));      // [1024][1024]
  ushort* qb  = (ushort*)(ws + (24ull << 20));      // [64][2048][64] (pre-scaled)
  ushort* kb  = (ushort*)(ws + (40ull << 20));      // [64][2048][64]
  ushort* vTb = (ushort*)(ws + (56ull << 20));      // [64][64][2048]
  ushort* aob = (ushort*)(ws + (72ull << 20));      // [8192][1024]

  cvt_x_kernel<<<(NB * TSEQ * CDIM / 4 + 255) / 256, 256, 0, stream>>>(
      (const float4*)x, (ushort4*)xb, NB * TSEQ * CDIM / 4);
  transpose_cvt_all<<<dim3(32, 32, 4), dim3(32, 8), 0, stream>>>(Wq, Wk, Wv, Wp, wall, wpT);

  // QKV: one merged GEMM, N = 3*16*64 = 3072 (wall rows = sel*1024 + h*64 + d)
  gemm_kernel<0><<<dim3(64 * 24), 256, 0, stream>>>(xb, wall, nullptr, nullptr, qb, kb, vTb);
  attn_kernel<<<dim3(1024), 256, 0, stream>>>(qb, kb, vTb, aob);
  gemm_kernel<1><<<dim3(64 * 8), 256, 0, stream>>>(aob, wpT, bp, out, nullptr, nullptr, nullptr);
}

// Round 11
// 182.433 us; speedup vs baseline: 1.1091x; 1.1091x over previous
//
#include <hip/hip_runtime.h>

#define TSEQ 2048
#define CDIM 1024
#define NH 16
#define DH 64
#define NB 4

typedef __bf16 bf16x8 __attribute__((ext_vector_type(8)));
typedef float f32x4 __attribute__((ext_vector_type(4)));

// 1/sqrt(C) * log2(e): folded into Q so softmax runs in exp2 domain
#define QSCALE 0.04508422f

static __device__ __forceinline__ ushort f2bf(float f) {
  unsigned u = __float_as_uint(f);
  unsigned r = u + 0x7fffu + ((u >> 16) & 1u);
  return (ushort)(r >> 16);
}

static __device__ __forceinline__ uint cvtpk(float lo, float hi) {
  uint r;
  asm("v_cvt_pk_bf16_f32 %0, %1, %2" : "=v"(r) : "v"(lo), "v"(hi));
  return r;
}

// global(16B, per-lane addr) -> LDS (wave-uniform base, HW adds lane*16)
static __device__ __forceinline__ void gload_lds16(const void* g, void* ldsbase) {
  __builtin_amdgcn_global_load_lds((const __attribute__((address_space(1))) void*)g,
                                   (__attribute__((address_space(3))) void*)ldsbase,
                                   16, 0, 0);
}

__global__ void cvt_x_kernel(const float4* __restrict__ src, ushort4* __restrict__ dst, int n4) {
  int i = blockIdx.x * blockDim.x + threadIdx.x;
  if (i >= n4) return;
  float4 f = src[i];
  ushort4 o;
  o.x = f2bf(f.x); o.y = f2bf(f.y); o.z = f2bf(f.z); o.w = f2bf(f.w);
  dst[i] = o;
}

// All weight transposes in ONE launch. z<3: W{q,k,v}[16][1024][64] -> wall slice
// [z][head][64][1024]; z==3: Wp[1024][1024] -> wpT[1024][1024].
__global__ void transpose_cvt_all(const float* __restrict__ Wq, const float* __restrict__ Wk,
                                  const float* __restrict__ Wv, const float* __restrict__ Wp,
                                  ushort* __restrict__ wall, ushort* __restrict__ wpT) {
  __shared__ float tile[32][33];
  const int z = blockIdx.z;
  const float* s; ushort* d; int Cc, c0, r0;
  if (z < 3) {
    const int head = blockIdx.x >> 1;
    s = (z == 0 ? Wq : z == 1 ? Wk : Wv) + (size_t)head * CDIM * DH;
    d = wall + ((size_t)z << 20) + (size_t)head * CDIM * DH;
    Cc = DH; c0 = (blockIdx.x & 1) * 32; r0 = blockIdx.y * 32;
  } else {
    s = Wp; d = wpT; Cc = CDIM; c0 = blockIdx.x * 32; r0 = blockIdx.y * 32;
  }
  const int tx = threadIdx.x, ty = threadIdx.y;
  for (int i = ty; i < 32; i += 8)
    tile[i][tx] = s[(size_t)(r0 + i) * Cc + c0 + tx];
  __syncthreads();
  for (int i = ty; i < 32; i += 8)
    d[(size_t)(c0 + i) * CDIM + r0 + tx] = f2bf(tile[tx][i]);
}

// 128x128-tile GEMM over A[8192][1024] @ B^T[N][1024], K=1024, BK=32.
// TRIPLE-BUFFERED (depth-2 prefetch): raw s_barrier + counted s_waitcnt vmcnt(4)
// (4 = gloads/wave/tile) so loads issued at step k are consumed at k+2 — two
// compute phases (~500cy) cover the load latency. Only the last step drains to 0.
// Rows are 64B; swizzle chunk ^= (row>>1)&3 is conflict-free on ds_read_b128.
// MODE 0: qkv (B^T = [3072][1024]; route by n). MODE 1: proj (f32 + bias).
// XCD chunk is nt-fastest: each XCD reads only 8 A-panels (2 MB, L2-resident).
template <int MODE>
__global__ __launch_bounds__(256) void gemm_kernel(
    const ushort* __restrict__ A, const ushort* __restrict__ Bt,
    const float* __restrict__ bp, float* __restrict__ fout,
    ushort* __restrict__ qb, ushort* __restrict__ kb, ushort* __restrict__ vTb) {
  __shared__ ushort lds[24576]; // 3 buf x (A 8KB + B 8KB) = 48KB
  const int tid = threadIdx.x, w = tid >> 6, l = tid & 63;
  const int nwg = gridDim.x;
  const int bid = blockIdx.x;
  const int wgid = (bid & 7) * (nwg >> 3) + (bid >> 3); // XCD swizzle (nwg % 8 == 0)
  const int NT = (MODE == 0) ? 24 : 8;
  const int nt = wgid % NT, mt = wgid / NT; // nt-fastest within an XCD chunk
  const int wr = w >> 1, wc = w & 1;
  const int srw = l >> 2;                      // row within a 16-row issue group
  const int sck = l & 3;                       // stored 16B chunk
  const int scol = (sck ^ ((srw >> 1) & 3)) * 8; // logical col (elems) this lane loads
  const int g = l >> 4;
  char* ldsb = (char*)lds;

  f32x4 acc[4][4] = {};

  const ushort* Arow = A + ((size_t)mt * 128) * CDIM;
  const ushort* Brow = Bt + ((size_t)nt * 128) * CDIM;

  // prologue: stage step 0 -> buf0, step 1 -> buf1 (order pinned between groups)
#pragma unroll
  for (int i = 0; i < 4; ++i) {
    int ch = w * 4 + i;
    const ushort* src = (ch < 8) ? Arow + (size_t)(ch * 16 + srw) * CDIM + scol
                                 : Brow + (size_t)((ch - 8) * 16 + srw) * CDIM + scol;
    gload_lds16(src, ldsb + ch * 1024);
  }
  asm volatile("" ::: "memory");
#pragma unroll
  for (int i = 0; i < 4; ++i) {
    int ch = w * 4 + i;
    const ushort* src = (ch < 8) ? Arow + (size_t)(ch * 16 + srw) * CDIM + 32 + scol
                                 : Brow + (size_t)((ch - 8) * 16 + srw) * CDIM + 32 + scol;
    gload_lds16(src, ldsb + 16384 + ch * 1024);
  }

  char* bc = ldsb;            // current buffer (step k)
  char* b1 = ldsb + 16384;    // step k+1 (in flight / ready)
  char* b2 = ldsb + 32768;    // step k+2 (prefetch target)
#pragma unroll 1
  for (int k0 = 0; k0 < CDIM; k0 += 32) {
    if (k0 + 32 < CDIM) asm volatile("s_waitcnt vmcnt(4)" ::: "memory");
    else                asm volatile("s_waitcnt vmcnt(0)" ::: "memory");
    __builtin_amdgcn_s_barrier();
    __builtin_amdgcn_sched_barrier(0);
    if (k0 + 64 < CDIM) { // prefetch step k+2 into b2 (readers of b2 passed barrier)
#pragma unroll
      for (int i = 0; i < 4; ++i) {
        int ch = w * 4 + i;
        const ushort* src = (ch < 8)
            ? Arow + (size_t)(ch * 16 + srw) * CDIM + k0 + 64 + scol
            : Brow + (size_t)((ch - 8) * 16 + srw) * CDIM + k0 + 64 + scol;
        gload_lds16(src, b2 + ch * 1024);
      }
    }
    bf16x8 af[4];
#pragma unroll
    for (int fm = 0; fm < 4; ++fm) {
      int row = wr * 64 + fm * 16 + (l & 15);
      af[fm] = *(const bf16x8*)(bc + row * 64 + ((g ^ ((row >> 1) & 3)) << 4));
    }
#pragma unroll
    for (int fn = 0; fn < 4; ++fn) {
      int n = wc * 64 + fn * 16 + (l & 15);
      bf16x8 bfr = *(const bf16x8*)(bc + 8192 + n * 64 + ((g ^ ((n >> 1) & 3)) << 4));
#pragma unroll
      for (int fm = 0; fm < 4; ++fm)
        acc[fm][fn] = __builtin_amdgcn_mfma_f32_16x16x32_bf16(af[fm], bfr, acc[fm][fn], 0, 0, 0);
    }
    char* t = bc; bc = b1; b1 = b2; b2 = t; // rotate buffers
  }

#pragma unroll
  for (int fm = 0; fm < 4; ++fm) {
#pragma unroll
    for (int fn = 0; fn < 4; ++fn) {
      const int gr0 = mt * 128 + wr * 64 + fm * 16 + (l >> 4) * 4;
      const int gc = nt * 128 + wc * 64 + fn * 16 + (l & 15);
      if (MODE == 1) {
        float bias = bp[gc];
#pragma unroll
        for (int r = 0; r < 4; ++r)
          fout[(size_t)(gr0 + r) * CDIM + gc] = acc[fm][fn][r] + bias;
      } else {
        const int sel = gc >> 10, h = (gc >> 6) & 15, d = gc & 63;
        const int bh = (gr0 >> 11) * NH + h, tl = gr0 & 2047;
        if (sel == 2) {
          ushort4 pk;
          pk.x = f2bf(acc[fm][fn][0]); pk.y = f2bf(acc[fm][fn][1]);
          pk.z = f2bf(acc[fm][fn][2]); pk.w = f2bf(acc[fm][fn][3]);
          *(ushort4*)(vTb + ((size_t)bh * DH + d) * TSEQ + tl) = pk;
        } else if (sel == 0) {
#pragma unroll
          for (int r = 0; r < 4; ++r)
            qb[((size_t)bh * TSEQ + tl + r) * DH + d] = f2bf(acc[fm][fn][r] * QSCALE);
        } else {
#pragma unroll
          for (int r = 0; r < 4; ++r)
            kb[((size_t)bh * TSEQ + tl + r) * DH + d] = f2bf(acc[fm][fn][r]);
        }
      }
    }
  }
}

// Flash attention: 1024 blocks x 256 threads (4 waves), one 128-q tile per block,
// qt-DESCENDING dispatch + XCD-aware bh grouping. Wave owns 32 q-rows (2 x 16-q
// subtiles sharing every K/V fragment read). KVBLK=64, TRIPLE-BUFFERED staging
// (depth-2 prefetch, counted vmcnt(4) + raw s_barrier; last tile drains to 0).
// Swapped QK^T: lane owns a q-row's k-slice. Softmax common path has NO cross-lane
// ops; lsum per-lane, reduced once at epilogue.
__global__ __launch_bounds__(256, 3) void attn_kernel(
    const ushort* __restrict__ qb, const ushort* __restrict__ kb,
    const ushort* __restrict__ vTb, ushort* __restrict__ aob) {
  __shared__ ushort lds[24576]; // K bufs 3x8KB @0, V bufs 3x8KB @byte 24576
  char* ldsb = (char*)lds;
  const int tid = threadIdx.x, w = tid >> 6, l = tid & 63;
  const int id = blockIdx.x;
  const int bh = (id & 7) * 8 + ((id >> 3) & 7); // XCD-aware bh grouping
  const int qt = 15 - (id >> 6);                 // big q-tiles dispatch first
  const int q0 = qt * 128;
  const int nt = 2 * (qt + 1);                   // # of 64-wide KV tiles (>= 2)
  const int b = bh >> 4, h = bh & 15;
  const int g = l >> 4, q = l & 15;
  const int srow = l >> 3;
  const int scol = (((l & 7) ^ srow) << 3);
  // bpermute byte-addrs: src lane = 32*(g&1) + 16*(j>=2) + q
  const int adrA = ((l & 16) << 1 | q) << 2;
  const int adrB = adrA + 64;
  const bool hi32 = (l & 32) != 0;

  bf16x8 qf[2][2]; // [qsub][ks]
#pragma unroll
  for (int qs = 0; qs < 2; ++qs) {
    const ushort* qrow = qb + ((size_t)bh * TSEQ + q0 + w * 32 + qs * 16 + q) * DH;
    qf[qs][0] = *(const bf16x8*)(qrow + 8 * g);
    qf[qs][1] = *(const bf16x8*)(qrow + 32 + 8 * g);
  }

  float m[2] = {0.f, 0.f}, lsum[2] = {0.f, 0.f}; // m=0 valid: branch fires if exceeded
  f32x4 o[4][2] = {};

  // prologue: tile 0 -> buf0, tile 1 -> buf1 (order pinned between groups)
#pragma unroll
  for (int i = 0; i < 4; ++i) {
    int ch = w * 4 + i;
    if (ch < 8)
      gload_lds16(kb + ((size_t)bh * TSEQ + ch * 8 + srow) * DH + scol, ldsb + ch * 1024);
    else {
      int d = (ch - 8) * 8 + srow;
      gload_lds16(vTb + ((size_t)bh * DH + d) * TSEQ + scol, ldsb + 24576 + (ch - 8) * 1024);
    }
  }
  asm volatile("" ::: "memory");
#pragma unroll
  for (int i = 0; i < 4; ++i) {
    int ch = w * 4 + i;
    if (ch < 8)
      gload_lds16(kb + ((size_t)bh * TSEQ + 64 + ch * 8 + srow) * DH + scol,
                  ldsb + 8192 + ch * 1024);
    else {
      int d = (ch - 8) * 8 + srow;
      gload_lds16(vTb + ((size_t)bh * DH + d) * TSEQ + 64 + scol,
                  ldsb + 24576 + 8192 + (ch - 8) * 1024);
    }
  }

  int oc = 0, o1 = 8192, o2 = 16384; // rotating byte offsets: tiles j, j+1, j+2
#pragma unroll 1
  for (int j = 0; j < nt; ++j) {
    if (j + 1 < nt) asm volatile("s_waitcnt vmcnt(4)" ::: "memory");
    else            asm volatile("s_waitcnt vmcnt(0)" ::: "memory");
    __builtin_amdgcn_s_barrier();
    __builtin_amdgcn_sched_barrier(0);
    if (j + 2 < nt) { // prefetch tile j+2 into o2 (its readers passed this barrier)
      const int kvn = (j + 2) * 64;
#pragma unroll
      for (int i = 0; i < 4; ++i) {
        int ch = w * 4 + i;
        if (ch < 8)
          gload_lds16(kb + ((size_t)bh * TSEQ + kvn + ch * 8 + srow) * DH + scol,
                      ldsb + o2 + ch * 1024);
        else {
          int d = (ch - 8) * 8 + srow;
          gload_lds16(vTb + ((size_t)bh * DH + d) * TSEQ + kvn + scol,
                      ldsb + 24576 + o2 + (ch - 8) * 1024);
        }
      }
    }
    char* Kb = ldsb + oc;
    char* Vb = ldsb + 24576 + oc;

    // S^T = K @ Q^T; s[fn][qs][r] = S[q-row q0+w*32+qs*16+q][k = j*64 + fn*16+4g+r]
    f32x4 s[4][2] = {};
    __builtin_amdgcn_s_setprio(1);
#pragma unroll
    for (int ks = 0; ks < 2; ++ks)
#pragma unroll
      for (int fn = 0; fn < 4; ++fn) {
        int n = fn * 16 + q;
        int cbb = (ks * 64 + 16 * g) ^ ((n & 7) << 4);
        bf16x8 kf = *(const bf16x8*)(Kb + n * 128 + cbb); // read once, feed both qsubs
        s[fn][0] = __builtin_amdgcn_mfma_f32_16x16x32_bf16(kf, qf[0][ks], s[fn][0], 0, 0, 0);
        s[fn][1] = __builtin_amdgcn_mfma_f32_16x16x32_bf16(kf, qf[1][ks], s[fn][1], 0, 0, 0);
      }
    __builtin_amdgcn_s_setprio(0);

    if (j >= nt - 2) { // only the diagonal band needs the causal mask
#pragma unroll
      for (int qs = 0; qs < 2; ++qs) {
        int rowloc = q0 + w * 32 + qs * 16 + q - j * 64; // may be negative (safe)
#pragma unroll
        for (int fn = 0; fn < 4; ++fn)
#pragma unroll
          for (int r = 0; r < 4; ++r)
            if (fn * 16 + 4 * g + r > rowloc) s[fn][qs][r] = -1e30f;
      }
    }

    // per-lane overflow check only (no cross-lane ops in the common path)
    float vmx[2];
#pragma unroll
    for (int qs = 0; qs < 2; ++qs) {
      float v = fmaxf(fmaxf(fmaxf(s[0][qs][0], s[0][qs][1]), fmaxf(s[0][qs][2], s[0][qs][3])),
                      fmaxf(fmaxf(s[1][qs][0], s[1][qs][1]), fmaxf(s[1][qs][2], s[1][qs][3])));
      v = fmaxf(v, fmaxf(fmaxf(fmaxf(s[2][qs][0], s[2][qs][1]), fmaxf(s[2][qs][2], s[2][qs][3])),
                         fmaxf(fmaxf(s[3][qs][0], s[3][qs][1]), fmaxf(s[3][qs][2], s[3][qs][3]))));
      vmx[qs] = v;
    }
    if (__any(fmaxf(vmx[0] - m[0], vmx[1] - m[1]) > 8.f)) { // rare: full reduce + rescale
      float fc[2];
#pragma unroll
      for (int qs = 0; qs < 2; ++qs) {
        float v = vmx[qs];
        v = fmaxf(v, __shfl_xor(v, 16));
        v = fmaxf(v, __shfl_xor(v, 32));
        float mn = fmaxf(m[qs], v);
        fc[qs] = __builtin_amdgcn_exp2f(m[qs] - mn);
        m[qs] = mn; lsum[qs] *= fc[qs];
      }
#pragma unroll
      for (int r = 0; r < 4; ++r) {
        float f0 = __shfl(fc[0], (l & 0x30) | (4 * g + r), 64);
        float f1 = __shfl(fc[1], (l & 0x30) | (4 * g + r), 64);
#pragma unroll
        for (int fn = 0; fn < 4; ++fn) { o[fn][0][r] *= f0; o[fn][1][r] *= f1; }
      }
    }

    uint D[2][4][2];
#pragma unroll
    for (int qs = 0; qs < 2; ++qs) {
      float rs = 0.f;
#pragma unroll
      for (int fn = 0; fn < 4; ++fn) {
        float p0 = __builtin_amdgcn_exp2f(s[fn][qs][0] - m[qs]);
        float p1 = __builtin_amdgcn_exp2f(s[fn][qs][1] - m[qs]);
        float p2 = __builtin_amdgcn_exp2f(s[fn][qs][2] - m[qs]);
        float p3 = __builtin_amdgcn_exp2f(s[fn][qs][3] - m[qs]);
        rs += (p0 + p1) + (p2 + p3);
        D[qs][fn][0] = cvtpk(p0, p1);
        D[qs][fn][1] = cvtpk(p2, p3);
      }
      lsum[qs] += rs; // per-lane partial; cross-lane reduce deferred to epilogue
    }

    // O += P @ V over 2 k-slices of 32; V fragment read once, feeds both qsubs
#pragma unroll
    for (int ksg = 0; ksg < 2; ++ksg) {
      union { uint u[4]; bf16x8 v; } P[2];
#pragma unroll
      for (int qs = 0; qs < 2; ++qs) {
        uint t0a = __builtin_amdgcn_ds_bpermute(adrA, (int)D[qs][2 * ksg][0]);
        uint t0b = __builtin_amdgcn_ds_bpermute(adrA, (int)D[qs][2 * ksg + 1][0]);
        uint t1a = __builtin_amdgcn_ds_bpermute(adrA, (int)D[qs][2 * ksg][1]);
        uint t1b = __builtin_amdgcn_ds_bpermute(adrA, (int)D[qs][2 * ksg + 1][1]);
        uint t2a = __builtin_amdgcn_ds_bpermute(adrB, (int)D[qs][2 * ksg][0]);
        uint t2b = __builtin_amdgcn_ds_bpermute(adrB, (int)D[qs][2 * ksg + 1][0]);
        uint t3a = __builtin_amdgcn_ds_bpermute(adrB, (int)D[qs][2 * ksg][1]);
        uint t3b = __builtin_amdgcn_ds_bpermute(adrB, (int)D[qs][2 * ksg + 1][1]);
        P[qs].u[0] = hi32 ? t0b : t0a;
        P[qs].u[1] = hi32 ? t1b : t1a;
        P[qs].u[2] = hi32 ? t2b : t2a;
        P[qs].u[3] = hi32 ? t3b : t3a;
      }
      __builtin_amdgcn_s_setprio(1);
#pragma unroll
      for (int fn = 0; fn < 4; ++fn) {
        int n = fn * 16 + q;
        int cbb = (ksg * 64 + 16 * g) ^ ((n & 7) << 4);
        bf16x8 vf = *(const bf16x8*)(Vb + n * 128 + cbb);
        o[fn][0] = __builtin_amdgcn_mfma_f32_16x16x32_bf16(P[0].v, vf, o[fn][0], 0, 0, 0);
        o[fn][1] = __builtin_amdgcn_mfma_f32_16x16x32_bf16(P[1].v, vf, o[fn][1], 0, 0, 0);
      }
      __builtin_amdgcn_s_setprio(0);
    }
    int t = oc; oc = o1; o1 = o2; o2 = t; // rotate buffers
  }

#pragma unroll
  for (int qs = 0; qs < 2; ++qs) {
    float tot = lsum[qs];                 // combine the 4 g-replica partial sums once
    tot += __shfl_xor(tot, 16);
    tot += __shfl_xor(tot, 32);
    float inv = 1.f / tot;                // per q-column l&15
#pragma unroll
    for (int r = 0; r < 4; ++r) {
      float invq = __shfl(inv, (l & 0x30) | (4 * g + r), 64);
      int t = q0 + w * 32 + qs * 16 + 4 * g + r;
#pragma unroll
      for (int fn = 0; fn < 4; ++fn) {
        int d = fn * 16 + q;
        aob[((size_t)b * TSEQ + t) * (NH * DH) + h * DH + d] = f2bf(o[fn][qs][r] * invq);
      }
    }
  }
}

extern "C" void kernel_launch(void* const* d_in, const int* in_sizes, int n_in,
                              void* d_out, int out_size, void* d_ws, size_t ws_size,
                              hipStream_t stream) {
  (void)in_sizes; (void)n_in; (void)out_size; (void)ws_size;
  const float* x  = (const float*)d_in[0];
  const float* Wq = (const float*)d_in[1];
  const float* Wk = (const float*)d_in[2];
  const float* Wv = (const float*)d_in[3];
  const float* Wp = (const float*)d_in[4];
  const float* bp = (const float*)d_in[5];
  float* out = (float*)d_out;
  char* ws = (char*)d_ws;

  ushort* xb  = (ushort*)(ws);                      // [8192][1024] bf16
  ushort* wall = (ushort*)(ws + (16ull << 20));     // [3072][1024] = Wq^T|Wk^T|Wv^T
  ushort* wpT = (ushort*)(ws + (22ull << 20));      // [1024][1024]
  ushort* qb  = (ushort*)(ws + (24ull << 20));      // [64][2048][64] (pre-scaled)
  ushort* kb  = (ushort*)(ws + (40ull << 20));      // [64][2048][64]
  ushort* vTb = (ushort*)(ws + (56ull << 20));      // [64][64][2048]
  ushort* aob = (ushort*)(ws + (72ull << 20));      // [8192][1024]

  cvt_x_kernel<<<(NB * TSEQ * CDIM / 4 + 255) / 256, 256, 0, stream>>>(
      (const float4*)x, (ushort4*)xb, NB * TSEQ * CDIM / 4);
  transpose_cvt_all<<<dim3(32, 32, 4), dim3(32, 8), 0, stream>>>(Wq, Wk, Wv, Wp, wall, wpT);

  // QKV: one merged GEMM, N = 3*16*64 = 3072 (wall rows = sel*1024 + h*64 + d)
  gemm_kernel<0><<<dim3(64 * 24), 256, 0, stream>>>(xb, wall, nullptr, nullptr, qb, kb, vTb);
  attn_kernel<<<dim3(1024), 256, 0, stream>>>(qb, kb, vTb, aob);
  gemm_kernel<1><<<dim3(64 * 8), 256, 0, stream>>>(aob, wpT, bp, out, nullptr, nullptr, nullptr);
}

// Round 12
// 173.822 us; speedup vs baseline: 1.1641x; 1.0495x over previous
//
#include <hip/hip_runtime.h>

#define TSEQ 2048
#define CDIM 1024
#define NH 16
#define DH 64
#define NB 4

typedef __bf16 bf16x8 __attribute__((ext_vector_type(8)));
typedef float f32x4 __attribute__((ext_vector_type(4)));

// 1/sqrt(C) * log2(e): folded into Q so softmax runs in exp2 domain
#define QSCALE 0.04508422f

static __device__ __forceinline__ ushort f2bf(float f) {
  unsigned u = __float_as_uint(f);
  unsigned r = u + 0x7fffu + ((u >> 16) & 1u);
  return (ushort)(r >> 16);
}

static __device__ __forceinline__ uint cvtpk(float lo, float hi) {
  uint r;
  asm("v_cvt_pk_bf16_f32 %0, %1, %2" : "=v"(r) : "v"(lo), "v"(hi));
  return r;
}

// global(16B, per-lane addr) -> LDS (wave-uniform base, HW adds lane*16)
static __device__ __forceinline__ void gload_lds16(const void* g, void* ldsbase) {
  __builtin_amdgcn_global_load_lds((const __attribute__((address_space(1))) void*)g,
                                   (__attribute__((address_space(3))) void*)ldsbase,
                                   16, 0, 0);
}

__global__ void cvt_x_kernel(const float4* __restrict__ src, ushort4* __restrict__ dst, int n4) {
  int i = blockIdx.x * blockDim.x + threadIdx.x;
  if (i >= n4) return;
  float4 f = src[i];
  ushort4 o;
  o.x = f2bf(f.x); o.y = f2bf(f.y); o.z = f2bf(f.z); o.w = f2bf(f.w);
  dst[i] = o;
}

// All weight transposes in ONE launch. z<3: W{q,k,v}[16][1024][64] -> wall slice
// [z][head][64][1024]; z==3: Wp[1024][1024] -> wpT[1024][1024].
__global__ void transpose_cvt_all(const float* __restrict__ Wq, const float* __restrict__ Wk,
                                  const float* __restrict__ Wv, const float* __restrict__ Wp,
                                  ushort* __restrict__ wall, ushort* __restrict__ wpT) {
  __shared__ float tile[32][33];
  const int z = blockIdx.z;
  const float* s; ushort* d; int Cc, c0, r0;
  if (z < 3) {
    const int head = blockIdx.x >> 1;
    s = (z == 0 ? Wq : z == 1 ? Wk : Wv) + (size_t)head * CDIM * DH;
    d = wall + ((size_t)z << 20) + (size_t)head * CDIM * DH;
    Cc = DH; c0 = (blockIdx.x & 1) * 32; r0 = blockIdx.y * 32;
  } else {
    s = Wp; d = wpT; Cc = CDIM; c0 = blockIdx.x * 32; r0 = blockIdx.y * 32;
  }
  const int tx = threadIdx.x, ty = threadIdx.y;
  for (int i = ty; i < 32; i += 8)
    tile[i][tx] = s[(size_t)(r0 + i) * Cc + c0 + tx];
  __syncthreads();
  for (int i = ty; i < 32; i += 8)
    d[(size_t)(c0 + i) * CDIM + r0 + tx] = f2bf(tile[tx][i]);
}

// QKV, phase-interleaved 256x256 tile (template T3+T4+T5 adapted to BK=32):
// 8 waves (2M x 4N), per-wave 128x64 output. 3 rotating K-tile slots (96KB LDS,
// slot = A[256][32] + B[256][32], 64B rows, XOR-chunk swizzle both sides).
// Per K-tile: 2 phases (M-half). Each phase: {4x ds_read_b128 A-frags (B-frags
// read once in phase 0, live in regs) | 2x global_load_lds staging of tile t+2}
// -> s_barrier -> lgkmcnt(0)+sched_barrier -> setprio(1) 16 MFMA setprio(0)
// -> s_barrier. vmcnt(4) ONCE per K-tile at phase 1 (tile t+1's 4 loads stay in
// flight across two phases); drains 0 only for the last two tiles.
__global__ __launch_bounds__(512, 2) void qkv8_kernel(
    const ushort* __restrict__ A, const ushort* __restrict__ Bt,
    ushort* __restrict__ qb, ushort* __restrict__ kb, ushort* __restrict__ vTb) {
  __shared__ ushort lds[49152]; // 3 slots x 32KB
  char* ldsb = (char*)lds;
  const int tid = threadIdx.x, w = tid >> 6, l = tid & 63;
  const int nwg = gridDim.x;            // 384
  const int bid = blockIdx.x;
  const int wgid = (bid & 7) * (nwg >> 3) + (bid >> 3); // XCD swizzle (384 % 8 == 0)
  const int nt = wgid % 12, mt = wgid / 12;             // nt-fastest within XCD chunk
  const int wr = w >> 2, wc = w & 3;    // 2M x 4N warp grid
  const int g = l >> 4;                 // 16B chunk index for ds_read
  const int scc = (l & 3) ^ ((l >> 3) & 3); // pre-swizzled source chunk (staging)
  const int strow = l >> 2;             // staging row within 16-row group

  f32x4 acc[8][4] = {};

  const ushort* Arow = A + ((size_t)mt * 256) * CDIM;
  const ushort* Brow = Bt + ((size_t)nt * 256) * CDIM;

  // prologue: stage tiles 0 and 1 (A then B each), then ensure tile 0 resident
#pragma unroll
  for (int tt = 0; tt < 2; ++tt) {
    char* sl = ldsb + tt * 32768;
#pragma unroll
    for (int i = 0; i < 2; ++i) {
      int ch = w * 2 + i;
      gload_lds16(Arow + (size_t)(ch * 16 + strow) * CDIM + tt * 32 + scc * 8, sl + ch * 1024);
    }
#pragma unroll
    for (int i = 0; i < 2; ++i) {
      int ch = w * 2 + i;
      gload_lds16(Brow + (size_t)(ch * 16 + strow) * CDIM + tt * 32 + scc * 8,
                  sl + 16384 + ch * 1024);
    }
  }
  asm volatile("s_waitcnt vmcnt(4)" ::: "memory"); // tile 0 complete; tile 1 in flight
  __builtin_amdgcn_s_barrier();

  char* sl0 = ldsb;           // tile t
  char* sl1 = ldsb + 32768;   // tile t+1
  char* sl2 = ldsb + 65536;   // tile t+2 (stage target; slot of tile t-1, freed)

#pragma unroll 1
  for (int t = 0; t < 32; ++t) {
    // ---------- phase 0 (M-half 0) ----------
    bf16x8 af[4], bf[4];
#pragma unroll
    for (int fm = 0; fm < 4; ++fm) {
      int row = wr * 128 + fm * 16 + (l & 15);
      af[fm] = *(const bf16x8*)(sl0 + row * 64 + ((g ^ ((row >> 1) & 3)) << 4));
    }
#pragma unroll
    for (int fn = 0; fn < 4; ++fn) {
      int n = wc * 64 + fn * 16 + (l & 15);
      bf[fn] = *(const bf16x8*)(sl0 + 16384 + n * 64 + ((g ^ ((n >> 1) & 3)) << 4));
    }
    if (t + 2 < 32) { // stage A of tile t+2
#pragma unroll
      for (int i = 0; i < 2; ++i) {
        int ch = w * 2 + i;
        gload_lds16(Arow + (size_t)(ch * 16 + strow) * CDIM + (t + 2) * 32 + scc * 8,
                    sl2 + ch * 1024);
      }
    }
    __builtin_amdgcn_s_barrier();
    asm volatile("s_waitcnt lgkmcnt(0)" ::: "memory");
    __builtin_amdgcn_sched_barrier(0);
    __builtin_amdgcn_s_setprio(1);
#pragma unroll
    for (int fn = 0; fn < 4; ++fn)
#pragma unroll
      for (int fm = 0; fm < 4; ++fm)
        acc[fm][fn] = __builtin_amdgcn_mfma_f32_16x16x32_bf16(af[fm], bf[fn], acc[fm][fn], 0, 0, 0);
    __builtin_amdgcn_s_setprio(0);
    __builtin_amdgcn_s_barrier();

    // ---------- phase 1 (M-half 1; B-frags still live in regs) ----------
    bf16x8 af1[4];
#pragma unroll
    for (int fm = 0; fm < 4; ++fm) {
      int row = wr * 128 + 64 + fm * 16 + (l & 15);
      af1[fm] = *(const bf16x8*)(sl0 + row * 64 + ((g ^ ((row >> 1) & 3)) << 4));
    }
    if (t + 2 < 32) { // stage B of tile t+2
#pragma unroll
      for (int i = 0; i < 2; ++i) {
        int ch = w * 2 + i;
        gload_lds16(Brow + (size_t)(ch * 16 + strow) * CDIM + (t + 2) * 32 + scc * 8,
                    sl2 + 16384 + ch * 1024);
      }
    }
    // counted wait: tile t+1's 4 loads (issued 2 phases ago) must complete before
    // next iteration's phase-0 ds_reads; everything newer (tile t+2: 4) stays in flight.
    if (t < 30)       asm volatile("s_waitcnt vmcnt(4)" ::: "memory");
    else if (t == 30) asm volatile("s_waitcnt vmcnt(0)" ::: "memory");
    __builtin_amdgcn_s_barrier();
    asm volatile("s_waitcnt lgkmcnt(0)" ::: "memory");
    __builtin_amdgcn_sched_barrier(0);
    __builtin_amdgcn_s_setprio(1);
#pragma unroll
    for (int fn = 0; fn < 4; ++fn)
#pragma unroll
      for (int fm = 0; fm < 4; ++fm)
        acc[4 + fm][fn] = __builtin_amdgcn_mfma_f32_16x16x32_bf16(af1[fm], bf[fn], acc[4 + fm][fn], 0, 0, 0);
    __builtin_amdgcn_s_setprio(0);
    __builtin_amdgcn_s_barrier();

    char* tmp = sl0; sl0 = sl1; sl1 = sl2; sl2 = tmp; // rotate slots
  }

  // epilogue: scatter to qb (pre-scaled) / kb / vT
#pragma unroll
  for (int fm2 = 0; fm2 < 8; ++fm2) {
#pragma unroll
    for (int fn = 0; fn < 4; ++fn) {
      const int gr0 = mt * 256 + wr * 128 + fm2 * 16 + (l >> 4) * 4;
      const int gc = nt * 256 + wc * 64 + fn * 16 + (l & 15);
      const int sel = gc >> 10, h = (gc >> 6) & 15, d = gc & 63;
      const int bh = (gr0 >> 11) * NH + h, tl = gr0 & 2047;
      if (sel == 2) {
        ushort4 pk;
        pk.x = f2bf(acc[fm2][fn][0]); pk.y = f2bf(acc[fm2][fn][1]);
        pk.z = f2bf(acc[fm2][fn][2]); pk.w = f2bf(acc[fm2][fn][3]);
        *(ushort4*)(vTb + ((size_t)bh * DH + d) * TSEQ + tl) = pk;
      } else if (sel == 0) {
#pragma unroll
        for (int r = 0; r < 4; ++r)
          qb[((size_t)bh * TSEQ + tl + r) * DH + d] = f2bf(acc[fm2][fn][r] * QSCALE);
      } else {
#pragma unroll
        for (int r = 0; r < 4; ++r)
          kb[((size_t)bh * TSEQ + tl + r) * DH + d] = f2bf(acc[fm2][fn][r]);
      }
    }
  }
}

// 128x128-tile GEMM (R9 structure): BK=32 double-buffer, one __syncthreads per
// step, stage(k+1) before compute(k). Used for the projection (MODE 1).
template <int MODE>
__global__ __launch_bounds__(256) void gemm_kernel(
    const ushort* __restrict__ A, const ushort* __restrict__ Bt,
    const float* __restrict__ bp, float* __restrict__ fout,
    ushort* __restrict__ qb, ushort* __restrict__ kb, ushort* __restrict__ vTb) {
  __shared__ ushort lds[16384]; // 2 buf x (A 8KB + B 8KB) = 32KB
  const int tid = threadIdx.x, w = tid >> 6, l = tid & 63;
  const int nwg = gridDim.x;
  const int bid = blockIdx.x;
  const int wgid = (bid & 7) * (nwg >> 3) + (bid >> 3);
  const int NT = (MODE == 0) ? 24 : 8;
  const int nt = wgid % NT, mt = wgid / NT;
  const int wr = w >> 1, wc = w & 1;
  const int srw = l >> 2;
  const int sck = l & 3;
  const int scol = (sck ^ ((srw >> 1) & 3)) * 8;
  const int g = l >> 4;
  char* ldsb = (char*)lds;

  f32x4 acc[4][4] = {};

  const ushort* Arow = A + ((size_t)mt * 128) * CDIM;
  const ushort* Brow = Bt + ((size_t)nt * 128) * CDIM;

#pragma unroll
  for (int i = 0; i < 4; ++i) {
    int ch = w * 4 + i;
    const ushort* src = (ch < 8) ? Arow + (size_t)(ch * 16 + srw) * CDIM + scol
                                 : Brow + (size_t)((ch - 8) * 16 + srw) * CDIM + scol;
    gload_lds16(src, ldsb + ch * 1024);
  }

  for (int k0 = 0; k0 < CDIM; k0 += 32) {
    const int bsel = (k0 >> 5) & 1;
    char* base = ldsb + bsel * 16384;
    __syncthreads();
    if (k0 + 32 < CDIM) {
      char* nb = ldsb + (bsel ^ 1) * 16384;
#pragma unroll
      for (int i = 0; i < 4; ++i) {
        int ch = w * 4 + i;
        const ushort* src = (ch < 8)
            ? Arow + (size_t)(ch * 16 + srw) * CDIM + k0 + 32 + scol
            : Brow + (size_t)((ch - 8) * 16 + srw) * CDIM + k0 + 32 + scol;
        gload_lds16(src, nb + ch * 1024);
      }
    }
    bf16x8 af[4];
#pragma unroll
    for (int fm = 0; fm < 4; ++fm) {
      int row = wr * 64 + fm * 16 + (l & 15);
      af[fm] = *(const bf16x8*)(base + row * 64 + ((g ^ ((row >> 1) & 3)) << 4));
    }
#pragma unroll
    for (int fn = 0; fn < 4; ++fn) {
      int n = wc * 64 + fn * 16 + (l & 15);
      bf16x8 bfr = *(const bf16x8*)(base + 8192 + n * 64 + ((g ^ ((n >> 1) & 3)) << 4));
#pragma unroll
      for (int fm = 0; fm < 4; ++fm)
        acc[fm][fn] = __builtin_amdgcn_mfma_f32_16x16x32_bf16(af[fm], bfr, acc[fm][fn], 0, 0, 0);
    }
  }

#pragma unroll
  for (int fm = 0; fm < 4; ++fm) {
#pragma unroll
    for (int fn = 0; fn < 4; ++fn) {
      const int gr0 = mt * 128 + wr * 64 + fm * 16 + (l >> 4) * 4;
      const int gc = nt * 128 + wc * 64 + fn * 16 + (l & 15);
      if (MODE == 1) {
        float bias = bp[gc];
#pragma unroll
        for (int r = 0; r < 4; ++r)
          fout[(size_t)(gr0 + r) * CDIM + gc] = acc[fm][fn][r] + bias;
      } else {
        const int sel = gc >> 10, h = (gc >> 6) & 15, d = gc & 63;
        const int bh = (gr0 >> 11) * NH + h, tl = gr0 & 2047;
        if (sel == 2) {
          ushort4 pk;
          pk.x = f2bf(acc[fm][fn][0]); pk.y = f2bf(acc[fm][fn][1]);
          pk.z = f2bf(acc[fm][fn][2]); pk.w = f2bf(acc[fm][fn][3]);
          *(ushort4*)(vTb + ((size_t)bh * DH + d) * TSEQ + tl) = pk;
        } else if (sel == 0) {
#pragma unroll
          for (int r = 0; r < 4; ++r)
            qb[((size_t)bh * TSEQ + tl + r) * DH + d] = f2bf(acc[fm][fn][r] * QSCALE);
        } else {
#pragma unroll
          for (int r = 0; r < 4; ++r)
            kb[((size_t)bh * TSEQ + tl + r) * DH + d] = f2bf(acc[fm][fn][r]);
        }
      }
    }
  }
}

// Flash attention (R9 structure): 1024 blocks x 256 threads (4 waves), 128-q tile,
// qt-descending + XCD-aware decode, KVBLK=64 double-buffered, swapped QK^T,
// no cross-lane ops in the softmax common path, lsum reduced at epilogue.
__global__ __launch_bounds__(256, 3) void attn_kernel(
    const ushort* __restrict__ qb, const ushort* __restrict__ kb,
    const ushort* __restrict__ vTb, ushort* __restrict__ aob) {
  __shared__ ushort lds[16384];
  char* ldsb = (char*)lds;
  const int tid = threadIdx.x, w = tid >> 6, l = tid & 63;
  const int id = blockIdx.x;
  const int bh = (id & 7) * 8 + ((id >> 3) & 7);
  const int qt = 15 - (id >> 6);
  const int q0 = qt * 128;
  const int nt = 2 * (qt + 1);
  const int b = bh >> 4, h = bh & 15;
  const int g = l >> 4, q = l & 15;
  const int srow = l >> 3;
  const int scol = (((l & 7) ^ srow) << 3);
  const int adrA = ((l & 16) << 1 | q) << 2;
  const int adrB = adrA + 64;
  const bool hi32 = (l & 32) != 0;

  bf16x8 qf[2][2];
#pragma unroll
  for (int qs = 0; qs < 2; ++qs) {
    const ushort* qrow = qb + ((size_t)bh * TSEQ + q0 + w * 32 + qs * 16 + q) * DH;
    qf[qs][0] = *(const bf16x8*)(qrow + 8 * g);
    qf[qs][1] = *(const bf16x8*)(qrow + 32 + 8 * g);
  }

  float m[2] = {0.f, 0.f}, lsum[2] = {0.f, 0.f};
  f32x4 o[4][2] = {};

#pragma unroll
  for (int i = 0; i < 4; ++i) {
    int ch = w * 4 + i;
    if (ch < 8)
      gload_lds16(kb + ((size_t)bh * TSEQ + ch * 8 + srow) * DH + scol, ldsb + ch * 1024);
    else {
      int d = (ch - 8) * 8 + srow;
      gload_lds16(vTb + ((size_t)bh * DH + d) * TSEQ + scol, ldsb + 16384 + (ch - 8) * 1024);
    }
  }

#pragma unroll 1
  for (int j = 0; j < nt; ++j) {
    __syncthreads();
    const int cbuf = j & 1;
    if (j + 1 < nt) {
      const int kvn = (j + 1) * 64, nb = (j + 1) & 1;
#pragma unroll
      for (int i = 0; i < 4; ++i) {
        int ch = w * 4 + i;
        if (ch < 8)
          gload_lds16(kb + ((size_t)bh * TSEQ + kvn + ch * 8 + srow) * DH + scol,
                      ldsb + nb * 8192 + ch * 1024);
        else {
          int d = (ch - 8) * 8 + srow;
          gload_lds16(vTb + ((size_t)bh * DH + d) * TSEQ + kvn + scol,
                      ldsb + 16384 + nb * 8192 + (ch - 8) * 1024);
        }
      }
    }
    char* Kb = ldsb + cbuf * 8192;
    char* Vb = ldsb + 16384 + cbuf * 8192;

    f32x4 s[4][2] = {};
    __builtin_amdgcn_s_setprio(1);
#pragma unroll
    for (int ks = 0; ks < 2; ++ks)
#pragma unroll
      for (int fn = 0; fn < 4; ++fn) {
        int n = fn * 16 + q;
        int cbb = (ks * 64 + 16 * g) ^ ((n & 7) << 4);
        bf16x8 kf = *(const bf16x8*)(Kb + n * 128 + cbb);
        s[fn][0] = __builtin_amdgcn_mfma_f32_16x16x32_bf16(kf, qf[0][ks], s[fn][0], 0, 0, 0);
        s[fn][1] = __builtin_amdgcn_mfma_f32_16x16x32_bf16(kf, qf[1][ks], s[fn][1], 0, 0, 0);
      }
    __builtin_amdgcn_s_setprio(0);

    if (j >= nt - 2) {
#pragma unroll
      for (int qs = 0; qs < 2; ++qs) {
        int rowloc = q0 + w * 32 + qs * 16 + q - j * 64;
#pragma unroll
        for (int fn = 0; fn < 4; ++fn)
#pragma unroll
          for (int r = 0; r < 4; ++r)
            if (fn * 16 + 4 * g + r > rowloc) s[fn][qs][r] = -1e30f;
      }
    }

    float vmx[2];
#pragma unroll
    for (int qs = 0; qs < 2; ++qs) {
      float v = fmaxf(fmaxf(fmaxf(s[0][qs][0], s[0][qs][1]), fmaxf(s[0][qs][2], s[0][qs][3])),
                      fmaxf(fmaxf(s[1][qs][0], s[1][qs][1]), fmaxf(s[1][qs][2], s[1][qs][3])));
      v = fmaxf(v, fmaxf(fmaxf(fmaxf(s[2][qs][0], s[2][qs][1]), fmaxf(s[2][qs][2], s[2][qs][3])),
                         fmaxf(fmaxf(s[3][qs][0], s[3][qs][1]), fmaxf(s[3][qs][2], s[3][qs][3]))));
      vmx[qs] = v;
    }
    if (__any(fmaxf(vmx[0] - m[0], vmx[1] - m[1]) > 8.f)) {
      float fc[2];
#pragma unroll
      for (int qs = 0; qs < 2; ++qs) {
        float v = vmx[qs];
        v = fmaxf(v, __shfl_xor(v, 16));
        v = fmaxf(v, __shfl_xor(v, 32));
        float mn = fmaxf(m[qs], v);
        fc[qs] = __builtin_amdgcn_exp2f(m[qs] - mn);
        m[qs] = mn; lsum[qs] *= fc[qs];
      }
#pragma unroll
      for (int r = 0; r < 4; ++r) {
        float f0 = __shfl(fc[0], (l & 0x30) | (4 * g + r), 64);
        float f1 = __shfl(fc[1], (l & 0x30) | (4 * g + r), 64);
#pragma unroll
        for (int fn = 0; fn < 4; ++fn) { o[fn][0][r] *= f0; o[fn][1][r] *= f1; }
      }
    }

    uint D[2][4][2];
#pragma unroll
    for (int qs = 0; qs < 2; ++qs) {
      float rs = 0.f;
#pragma unroll
      for (int fn = 0; fn < 4; ++fn) {
        float p0 = __builtin_amdgcn_exp2f(s[fn][qs][0] - m[qs]);
        float p1 = __builtin_amdgcn_exp2f(s[fn][qs][1] - m[qs]);
        float p2 = __builtin_amdgcn_exp2f(s[fn][qs][2] - m[qs]);
        float p3 = __builtin_amdgcn_exp2f(s[fn][qs][3] - m[qs]);
        rs += (p0 + p1) + (p2 + p3);
        D[qs][fn][0] = cvtpk(p0, p1);
        D[qs][fn][1] = cvtpk(p2, p3);
      }
      lsum[qs] += rs;
    }

#pragma unroll
    for (int ksg = 0; ksg < 2; ++ksg) {
      union { uint u[4]; bf16x8 v; } P[2];
#pragma unroll
      for (int qs = 0; qs < 2; ++qs) {
        uint t0a = __builtin_amdgcn_ds_bpermute(adrA, (int)D[qs][2 * ksg][0]);
        uint t0b = __builtin_amdgcn_ds_bpermute(adrA, (int)D[qs][2 * ksg + 1][0]);
        uint t1a = __builtin_amdgcn_ds_bpermute(adrA, (int)D[qs][2 * ksg][1]);
        uint t1b = __builtin_amdgcn_ds_bpermute(adrA, (int)D[qs][2 * ksg + 1][1]);
        uint t2a = __builtin_amdgcn_ds_bpermute(adrB, (int)D[qs][2 * ksg][0]);
        uint t2b = __builtin_amdgcn_ds_bpermute(adrB, (int)D[qs][2 * ksg + 1][0]);
        uint t3a = __builtin_amdgcn_ds_bpermute(adrB, (int)D[qs][2 * ksg][1]);
        uint t3b = __builtin_amdgcn_ds_bpermute(adrB, (int)D[qs][2 * ksg + 1][1]);
        P[qs].u[0] = hi32 ? t0b : t0a;
        P[qs].u[1] = hi32 ? t1b : t1a;
        P[qs].u[2] = hi32 ? t2b : t2a;
        P[qs].u[3] = hi32 ? t3b : t3a;
      }
      __builtin_amdgcn_s_setprio(1);
#pragma unroll
      for (int fn = 0; fn < 4; ++fn) {
        int n = fn * 16 + q;
        int cbb = (ksg * 64 + 16 * g) ^ ((n & 7) << 4);
        bf16x8 vf = *(const bf16x8*)(Vb + n * 128 + cbb);
        o[fn][0] = __builtin_amdgcn_mfma_f32_16x16x32_bf16(P[0].v, vf, o[fn][0], 0, 0, 0);
        o[fn][1] = __builtin_amdgcn_mfma_f32_16x16x32_bf16(P[1].v, vf, o[fn][1], 0, 0, 0);
      }
      __builtin_amdgcn_s_setprio(0);
    }
  }

#pragma unroll
  for (int qs = 0; qs < 2; ++qs) {
    float tot = lsum[qs];
    tot += __shfl_xor(tot, 16);
    tot += __shfl_xor(tot, 32);
    float inv = 1.f / tot;
#pragma unroll
    for (int r = 0; r < 4; ++r) {
      float invq = __shfl(inv, (l & 0x30) | (4 * g + r), 64);
      int t = q0 + w * 32 + qs * 16 + 4 * g + r;
#pragma unroll
      for (int fn = 0; fn < 4; ++fn) {
        int d = fn * 16 + q;
        aob[((size_t)b * TSEQ + t) * (NH * DH) + h * DH + d] = f2bf(o[fn][qs][r] * invq);
      }
    }
  }
}

extern "C" void kernel_launch(void* const* d_in, const int* in_sizes, int n_in,
                              void* d_out, int out_size, void* d_ws, size_t ws_size,
                              hipStream_t stream) {
  (void)in_sizes; (void)n_in; (void)out_size; (void)ws_size;
  const float* x  = (const float*)d_in[0];
  const float* Wq = (const float*)d_in[1];
  const float* Wk = (const float*)d_in[2];
  const float* Wv = (const float*)d_in[3];
  const float* Wp = (const float*)d_in[4];
  const float* bp = (const float*)d_in[5];
  float* out = (float*)d_out;
  char* ws = (char*)d_ws;

  ushort* xb  = (ushort*)(ws);                      // [8192][1024] bf16
  ushort* wall = (ushort*)(ws + (16ull << 20));     // [3072][1024] = Wq^T|Wk^T|Wv^T
  ushort* wpT = (ushort*)(ws + (22ull << 20));      // [1024][1024]
  ushort* qb  = (ushort*)(ws + (24ull << 20));      // [64][2048][64] (pre-scaled)
  ushort* kb  = (ushort*)(ws + (40ull << 20));      // [64][2048][64]
  ushort* vTb = (ushort*)(ws + (56ull << 20));      // [64][64][2048]
  ushort* aob = (ushort*)(ws + (72ull << 20));      // [8192][1024]

  cvt_x_kernel<<<(NB * TSEQ * CDIM / 4 + 255) / 256, 256, 0, stream>>>(
      (const float4*)x, (ushort4*)xb, NB * TSEQ * CDIM / 4);
  transpose_cvt_all<<<dim3(32, 32, 4), dim3(32, 8), 0, stream>>>(Wq, Wk, Wv, Wp, wall, wpT);

  // QKV: phase-interleaved 256^2 kernel; grid 32 m-tiles x 12 n-tiles = 384 (%8==0)
  qkv8_kernel<<<dim3(384), 512, 0, stream>>>(xb, wall, qb, kb, vTb);
  attn_kernel<<<dim3(1024), 256, 0, stream>>>(qb, kb, vTb, aob);
  gemm_kernel<1><<<dim3(64 * 8), 256, 0, stream>>>(aob, wpT, bp, out, nullptr, nullptr, nullptr);
}

// Round 13
// 172.837 us; speedup vs baseline: 1.1707x; 1.0057x over previous
//
#include <hip/hip_runtime.h>

#define TSEQ 2048
#define CDIM 1024
#define NH 16
#define DH 64
#define NB 4

typedef __bf16 bf16x8 __attribute__((ext_vector_type(8)));
typedef float f32x4 __attribute__((ext_vector_type(4)));

// 1/sqrt(C) * log2(e): folded into Q so softmax runs in exp2 domain
#define QSCALE 0.04508422f

static __device__ __forceinline__ ushort f2bf(float f) {
  unsigned u = __float_as_uint(f);
  unsigned r = u + 0x7fffu + ((u >> 16) & 1u);
  return (ushort)(r >> 16);
}

static __device__ __forceinline__ uint cvtpk(float lo, float hi) {
  uint r;
  asm("v_cvt_pk_bf16_f32 %0, %1, %2" : "=v"(r) : "v"(lo), "v"(hi));
  return r;
}

// global(16B, per-lane addr) -> LDS (wave-uniform base, HW adds lane*16)
static __device__ __forceinline__ void gload_lds16(const void* g, void* ldsbase) {
  __builtin_amdgcn_global_load_lds((const __attribute__((address_space(1))) void*)g,
                                   (__attribute__((address_space(3))) void*)ldsbase,
                                   16, 0, 0);
}

// ONE prep launch. z<3: W{q,k,v}[16][1024][64] -> wall [z][head][64][1024];
// z==3: Wp -> wpT; z in [4,12): x f32 -> xb bf16 (plane p covers 1024 blocks
// x 256 threads x float4 = 1M elems; 8 planes = 8.4M = NB*TSEQ*CDIM exactly).
__global__ void prep_kernel(const float* __restrict__ x,
                            const float* __restrict__ Wq, const float* __restrict__ Wk,
                            const float* __restrict__ Wv, const float* __restrict__ Wp,
                            ushort* __restrict__ xb, ushort* __restrict__ wall,
                            ushort* __restrict__ wpT) {
  __shared__ float tile[32][33];
  const int z = blockIdx.z;
  const int tx = threadIdx.x, ty = threadIdx.y;
  if (z >= 4) {
    int blk = (z - 4) * 1024 + blockIdx.y * 32 + blockIdx.x;
    int i = blk * 256 + ty * 32 + tx;
    float4 f = ((const float4*)x)[i];
    ushort4 o;
    o.x = f2bf(f.x); o.y = f2bf(f.y); o.z = f2bf(f.z); o.w = f2bf(f.w);
    ((ushort4*)xb)[i] = o;
    return;
  }
  const float* s; ushort* d; int Cc, c0, r0;
  if (z < 3) {
    const int head = blockIdx.x >> 1;
    s = (z == 0 ? Wq : z == 1 ? Wk : Wv) + (size_t)head * CDIM * DH;
    d = wall + ((size_t)z << 20) + (size_t)head * CDIM * DH;
    Cc = DH; c0 = (blockIdx.x & 1) * 32; r0 = blockIdx.y * 32;
  } else {
    s = Wp; d = wpT; Cc = CDIM; c0 = blockIdx.x * 32; r0 = blockIdx.y * 32;
  }
  for (int i = ty; i < 32; i += 8)
    tile[i][tx] = s[(size_t)(r0 + i) * Cc + c0 + tx];
  __syncthreads();
  for (int i = ty; i < 32; i += 8)
    d[(size_t)(c0 + i) * CDIM + r0 + tx] = f2bf(tile[tx][i]);
}

// 128x128-tile GEMM (R9 structure, best measured): BK=32 double-buffer at 32KB
// LDS, one __syncthreads per step, stage(k+1) issued before compute(k).
// Rows are 64B; swizzle chunk ^= (row>>1)&3 is conflict-free on ds_read_b128.
// MODE 0: qkv (B^T = [3072][1024]; route by n). MODE 1: proj (f32 + bias).
// XCD chunk is nt-fastest: each XCD reads only 8 A-panels (2 MB, L2-resident).
template <int MODE>
__global__ __launch_bounds__(256) void gemm_kernel(
    const ushort* __restrict__ A, const ushort* __restrict__ Bt,
    const float* __restrict__ bp, float* __restrict__ fout,
    ushort* __restrict__ qb, ushort* __restrict__ kb, ushort* __restrict__ vTb) {
  __shared__ ushort lds[16384]; // 2 buf x (A 8KB + B 8KB) = 32KB
  const int tid = threadIdx.x, w = tid >> 6, l = tid & 63;
  const int nwg = gridDim.x;
  const int bid = blockIdx.x;
  const int wgid = (bid & 7) * (nwg >> 3) + (bid >> 3);
  const int NT = (MODE == 0) ? 24 : 8;
  const int nt = wgid % NT, mt = wgid / NT;
  const int wr = w >> 1, wc = w & 1;
  const int srw = l >> 2;
  const int sck = l & 3;
  const int scol = (sck ^ ((srw >> 1) & 3)) * 8;
  const int g = l >> 4;
  char* ldsb = (char*)lds;

  f32x4 acc[4][4] = {};

  const ushort* Arow = A + ((size_t)mt * 128) * CDIM;
  const ushort* Brow = Bt + ((size_t)nt * 128) * CDIM;

#pragma unroll
  for (int i = 0; i < 4; ++i) {
    int ch = w * 4 + i;
    const ushort* src = (ch < 8) ? Arow + (size_t)(ch * 16 + srw) * CDIM + scol
                                 : Brow + (size_t)((ch - 8) * 16 + srw) * CDIM + scol;
    gload_lds16(src, ldsb + ch * 1024);
  }

  for (int k0 = 0; k0 < CDIM; k0 += 32) {
    const int bsel = (k0 >> 5) & 1;
    char* base = ldsb + bsel * 16384;
    __syncthreads();
    if (k0 + 32 < CDIM) {
      char* nb = ldsb + (bsel ^ 1) * 16384;
#pragma unroll
      for (int i = 0; i < 4; ++i) {
        int ch = w * 4 + i;
        const ushort* src = (ch < 8)
            ? Arow + (size_t)(ch * 16 + srw) * CDIM + k0 + 32 + scol
            : Brow + (size_t)((ch - 8) * 16 + srw) * CDIM + k0 + 32 + scol;
        gload_lds16(src, nb + ch * 1024);
      }
    }
    bf16x8 af[4];
#pragma unroll
    for (int fm = 0; fm < 4; ++fm) {
      int row = wr * 64 + fm * 16 + (l & 15);
      af[fm] = *(const bf16x8*)(base + row * 64 + ((g ^ ((row >> 1) & 3)) << 4));
    }
#pragma unroll
    for (int fn = 0; fn < 4; ++fn) {
      int n = wc * 64 + fn * 16 + (l & 15);
      bf16x8 bfr = *(const bf16x8*)(base + 8192 + n * 64 + ((g ^ ((n >> 1) & 3)) << 4));
#pragma unroll
      for (int fm = 0; fm < 4; ++fm)
        acc[fm][fn] = __builtin_amdgcn_mfma_f32_16x16x32_bf16(af[fm], bfr, acc[fm][fn], 0, 0, 0);
    }
  }

#pragma unroll
  for (int fm = 0; fm < 4; ++fm) {
#pragma unroll
    for (int fn = 0; fn < 4; ++fn) {
      const int gr0 = mt * 128 + wr * 64 + fm * 16 + (l >> 4) * 4;
      const int gc = nt * 128 + wc * 64 + fn * 16 + (l & 15);
      if (MODE == 1) {
        float bias = bp[gc];
#pragma unroll
        for (int r = 0; r < 4; ++r)
          fout[(size_t)(gr0 + r) * CDIM + gc] = acc[fm][fn][r] + bias;
      } else {
        const int sel = gc >> 10, h = (gc >> 6) & 15, d = gc & 63;
        const int bh = (gr0 >> 11) * NH + h, tl = gr0 & 2047;
        if (sel == 2) {
          ushort4 pk;
          pk.x = f2bf(acc[fm][fn][0]); pk.y = f2bf(acc[fm][fn][1]);
          pk.z = f2bf(acc[fm][fn][2]); pk.w = f2bf(acc[fm][fn][3]);
          *(ushort4*)(vTb + ((size_t)bh * DH + d) * TSEQ + tl) = pk;
        } else if (sel == 0) {
#pragma unroll
          for (int r = 0; r < 4; ++r)
            qb[((size_t)bh * TSEQ + tl + r) * DH + d] = f2bf(acc[fm][fn][r] * QSCALE);
        } else {
#pragma unroll
          for (int r = 0; r < 4; ++r)
            kb[((size_t)bh * TSEQ + tl + r) * DH + d] = f2bf(acc[fm][fn][r]);
        }
      }
    }
  }
}

// Flash attention (R9 structure, verified): 1024 blocks x 256 threads (4 waves),
// 128-q tile, qt-descending + XCD-aware decode, KVBLK=64 double-buffered,
// swapped QK^T, no cross-lane ops in the softmax common path.
__global__ __launch_bounds__(256, 3) void attn_kernel(
    const ushort* __restrict__ qb, const ushort* __restrict__ kb,
    const ushort* __restrict__ vTb, ushort* __restrict__ aob) {
  __shared__ ushort lds[16384];
  char* ldsb = (char*)lds;
  const int tid = threadIdx.x, w = tid >> 6, l = tid & 63;
  const int id = blockIdx.x;
  const int bh = (id & 7) * 8 + ((id >> 3) & 7);
  const int qt = 15 - (id >> 6);
  const int q0 = qt * 128;
  const int nt = 2 * (qt + 1);
  const int b = bh >> 4, h = bh & 15;
  const int g = l >> 4, q = l & 15;
  const int srow = l >> 3;
  const int scol = (((l & 7) ^ srow) << 3);
  const int adrA = ((l & 16) << 1 | q) << 2;
  const int adrB = adrA + 64;
  const bool hi32 = (l & 32) != 0;

  bf16x8 qf[2][2];
#pragma unroll
  for (int qs = 0; qs < 2; ++qs) {
    const ushort* qrow = qb + ((size_t)bh * TSEQ + q0 + w * 32 + qs * 16 + q) * DH;
    qf[qs][0] = *(const bf16x8*)(qrow + 8 * g);
    qf[qs][1] = *(const bf16x8*)(qrow + 32 + 8 * g);
  }

  float m[2] = {0.f, 0.f}, lsum[2] = {0.f, 0.f};
  f32x4 o[4][2] = {};

#pragma unroll
  for (int i = 0; i < 4; ++i) {
    int ch = w * 4 + i;
    if (ch < 8)
      gload_lds16(kb + ((size_t)bh * TSEQ + ch * 8 + srow) * DH + scol, ldsb + ch * 1024);
    else {
      int d = (ch - 8) * 8 + srow;
      gload_lds16(vTb + ((size_t)bh * DH + d) * TSEQ + scol, ldsb + 16384 + (ch - 8) * 1024);
    }
  }

#pragma unroll 1
  for (int j = 0; j < nt; ++j) {
    __syncthreads();
    const int cbuf = j & 1;
    if (j + 1 < nt) {
      const int kvn = (j + 1) * 64, nb = (j + 1) & 1;
#pragma unroll
      for (int i = 0; i < 4; ++i) {
        int ch = w * 4 + i;
        if (ch < 8)
          gload_lds16(kb + ((size_t)bh * TSEQ + kvn + ch * 8 + srow) * DH + scol,
                      ldsb + nb * 8192 + ch * 1024);
        else {
          int d = (ch - 8) * 8 + srow;
          gload_lds16(vTb + ((size_t)bh * DH + d) * TSEQ + kvn + scol,
                      ldsb + 16384 + nb * 8192 + (ch - 8) * 1024);
        }
      }
    }
    char* Kb = ldsb + cbuf * 8192;
    char* Vb = ldsb + 16384 + cbuf * 8192;

    f32x4 s[4][2] = {};
    __builtin_amdgcn_s_setprio(1);
#pragma unroll
    for (int ks = 0; ks < 2; ++ks)
#pragma unroll
      for (int fn = 0; fn < 4; ++fn) {
        int n = fn * 16 + q;
        int cbb = (ks * 64 + 16 * g) ^ ((n & 7) << 4);
        bf16x8 kf = *(const bf16x8*)(Kb + n * 128 + cbb);
        s[fn][0] = __builtin_amdgcn_mfma_f32_16x16x32_bf16(kf, qf[0][ks], s[fn][0], 0, 0, 0);
        s[fn][1] = __builtin_amdgcn_mfma_f32_16x16x32_bf16(kf, qf[1][ks], s[fn][1], 0, 0, 0);
      }
    __builtin_amdgcn_s_setprio(0);

    if (j >= nt - 2) {
#pragma unroll
      for (int qs = 0; qs < 2; ++qs) {
        int rowloc = q0 + w * 32 + qs * 16 + q - j * 64;
#pragma unroll
        for (int fn = 0; fn < 4; ++fn)
#pragma unroll
          for (int r = 0; r < 4; ++r)
            if (fn * 16 + 4 * g + r > rowloc) s[fn][qs][r] = -1e30f;
      }
    }

    float vmx[2];
#pragma unroll
    for (int qs = 0; qs < 2; ++qs) {
      float v = fmaxf(fmaxf(fmaxf(s[0][qs][0], s[0][qs][1]), fmaxf(s[0][qs][2], s[0][qs][3])),
                      fmaxf(fmaxf(s[1][qs][0], s[1][qs][1]), fmaxf(s[1][qs][2], s[1][qs][3])));
      v = fmaxf(v, fmaxf(fmaxf(fmaxf(s[2][qs][0], s[2][qs][1]), fmaxf(s[2][qs][2], s[2][qs][3])),
                         fmaxf(fmaxf(s[3][qs][0], s[3][qs][1]), fmaxf(s[3][qs][2], s[3][qs][3]))));
      vmx[qs] = v;
    }
    if (__any(fmaxf(vmx[0] - m[0], vmx[1] - m[1]) > 8.f)) {
      float fc[2];
#pragma unroll
      for (int qs = 0; qs < 2; ++qs) {
        float v = vmx[qs];
        v = fmaxf(v, __shfl_xor(v, 16));
        v = fmaxf(v, __shfl_xor(v, 32));
        float mn = fmaxf(m[qs], v);
        fc[qs] = __builtin_amdgcn_exp2f(m[qs] - mn);
        m[qs] = mn; lsum[qs] *= fc[qs];
      }
#pragma unroll
      for (int r = 0; r < 4; ++r) {
        float f0 = __shfl(fc[0], (l & 0x30) | (4 * g + r), 64);
        float f1 = __shfl(fc[1], (l & 0x30) | (4 * g + r), 64);
#pragma unroll
        for (int fn = 0; fn < 4; ++fn) { o[fn][0][r] *= f0; o[fn][1][r] *= f1; }
      }
    }

    uint D[2][4][2];
#pragma unroll
    for (int qs = 0; qs < 2; ++qs) {
      float rs = 0.f;
#pragma unroll
      for (int fn = 0; fn < 4; ++fn) {
        float p0 = __builtin_amdgcn_exp2f(s[fn][qs][0] - m[qs]);
        float p1 = __builtin_amdgcn_exp2f(s[fn][qs][1] - m[qs]);
        float p2 = __builtin_amdgcn_exp2f(s[fn][qs][2] - m[qs]);
        float p3 = __builtin_amdgcn_exp2f(s[fn][qs][3] - m[qs]);
        rs += (p0 + p1) + (p2 + p3);
        D[qs][fn][0] = cvtpk(p0, p1);
        D[qs][fn][1] = cvtpk(p2, p3);
      }
      lsum[qs] += rs;
    }

#pragma unroll
    for (int ksg = 0; ksg < 2; ++ksg) {
      union { uint u[4]; bf16x8 v; } P[2];
#pragma unroll
      for (int qs = 0; qs < 2; ++qs) {
        uint t0a = __builtin_amdgcn_ds_bpermute(adrA, (int)D[qs][2 * ksg][0]);
        uint t0b = __builtin_amdgcn_ds_bpermute(adrA, (int)D[qs][2 * ksg + 1][0]);
        uint t1a = __builtin_amdgcn_ds_bpermute(adrA, (int)D[qs][2 * ksg][1]);
        uint t1b = __builtin_amdgcn_ds_bpermute(adrA, (int)D[qs][2 * ksg + 1][1]);
        uint t2a = __builtin_amdgcn_ds_bpermute(adrB, (int)D[qs][2 * ksg][0]);
        uint t2b = __builtin_amdgcn_ds_bpermute(adrB, (int)D[qs][2 * ksg + 1][0]);
        uint t3a = __builtin_amdgcn_ds_bpermute(adrB, (int)D[qs][2 * ksg][1]);
        uint t3b = __builtin_amdgcn_ds_bpermute(adrB, (int)D[qs][2 * ksg + 1][1]);
        P[qs].u[0] = hi32 ? t0b : t0a;
        P[qs].u[1] = hi32 ? t1b : t1a;
        P[qs].u[2] = hi32 ? t2b : t2a;
        P[qs].u[3] = hi32 ? t3b : t3a;
      }
      __builtin_amdgcn_s_setprio(1);
#pragma unroll
      for (int fn = 0; fn < 4; ++fn) {
        int n = fn * 16 + q;
        int cbb = (ksg * 64 + 16 * g) ^ ((n & 7) << 4);
        bf16x8 vf = *(const bf16x8*)(Vb + n * 128 + cbb);
        o[fn][0] = __builtin_amdgcn_mfma_f32_16x16x32_bf16(P[0].v, vf, o[fn][0], 0, 0, 0);
        o[fn][1] = __builtin_amdgcn_mfma_f32_16x16x32_bf16(P[1].v, vf, o[fn][1], 0, 0, 0);
      }
      __builtin_amdgcn_s_setprio(0);
    }
  }

#pragma unroll
  for (int qs = 0; qs < 2; ++qs) {
    float tot = lsum[qs];
    tot += __shfl_xor(tot, 16);
    tot += __shfl_xor(tot, 32);
    float inv = 1.f / tot;
#pragma unroll
    for (int r = 0; r < 4; ++r) {
      float invq = __shfl(inv, (l & 0x30) | (4 * g + r), 64);
      int t = q0 + w * 32 + qs * 16 + 4 * g + r;
#pragma unroll
      for (int fn = 0; fn < 4; ++fn) {
        int d = fn * 16 + q;
        aob[((size_t)b * TSEQ + t) * (NH * DH) + h * DH + d] = f2bf(o[fn][qs][r] * invq);
      }
    }
  }
}

extern "C" void kernel_launch(void* const* d_in, const int* in_sizes, int n_in,
                              void* d_out, int out_size, void* d_ws, size_t ws_size,
                              hipStream_t stream) {
  (void)in_sizes; (void)n_in; (void)out_size; (void)ws_size;
  const float* x  = (const float*)d_in[0];
  const float* Wq = (const float*)d_in[1];
  const float* Wk = (const float*)d_in[2];
  const float* Wv = (const float*)d_in[3];
  const float* Wp = (const float*)d_in[4];
  const float* bp = (const float*)d_in[5];
  float* out = (float*)d_out;
  char* ws = (char*)d_ws;

  ushort* xb  = (ushort*)(ws);                      // [8192][1024] bf16
  ushort* wall = (ushort*)(ws + (16ull << 20));     // [3072][1024] = Wq^T|Wk^T|Wv^T
  ushort* wpT = (ushort*)(ws + (22ull << 20));      // [1024][1024]
  ushort* qb  = (ushort*)(ws + (24ull << 20));      // [64][2048][64] (pre-scaled)
  ushort* kb  = (ushort*)(ws + (40ull << 20));      // [64][2048][64]
  ushort* vTb = (ushort*)(ws + (56ull << 20));      // [64][64][2048]
  ushort* aob = (ushort*)(ws + (72ull << 20));      // [8192][1024]

  prep_kernel<<<dim3(32, 32, 12), dim3(32, 8), 0, stream>>>(x, Wq, Wk, Wv, Wp, xb, wall, wpT);

  // QKV: one merged GEMM, N = 3*16*64 = 3072 (wall rows = sel*1024 + h*64 + d)
  gemm_kernel<0><<<dim3(64 * 24), 256, 0, stream>>>(xb, wall, nullptr, nullptr, qb, kb, vTb);
  attn_kernel<<<dim3(1024), 256, 0, stream>>>(qb, kb, vTb, aob);
  gemm_kernel<1><<<dim3(64 * 8), 256, 0, stream>>>(aob, wpT, bp, out, nullptr, nullptr, nullptr);
}